// Round 4
// baseline (217.677 us; speedup 1.0000x reference)
//
#include <hip/hip_runtime.h>
#include <math.h>

// Problem constants (from reference)
#define T_STEPS 256
#define N_NEUR  2048
#define N_BATCH 32
#define STRIDE  (2 * N_NEUR)   // input floats per (b, t)

#define TT      16             // timesteps per LDS tile
#define NTILE   (T_STEPS / TT) // 16 tiles
#define BN      64             // neurons per block (1 wave per block)

// Async 16B global->LDS DMA (global_load_lds_dwordx4). Global address is
// per-lane; LDS destination is wave-uniform base + lane*16.
__device__ __forceinline__ void async_cp16(const float* g, float* l) {
    __builtin_amdgcn_global_load_lds(
        (const __attribute__((address_space(1))) void*)g,
        (__attribute__((address_space(3))) void*)l,
        16, 0, 0);
}

// R4: same depth-1 DMA pipeline as R3, but 1-wave blocks x 1024 -> 4
// independent blocks per CU. R3 showed the __syncthreads vmcnt(0) drain
// makes each block's pipeline bursty (60% of per-CU BW); four unsynchronized
// blocks per CU keep the memory pipe continuously fed (m114 overlap).
//
// fp discipline: __fmul_rn/__fadd_rn keep mul/add separately rounded
// (reference does not contract to FMA); binary outputs flip on ulp drift.
// Verified absmax=0.0 in R1-R3 — do not touch the arithmetic.
__global__ __launch_bounds__(64) void snn_scan_kernel(
    const float* __restrict__ in,
    float* __restrict__ out,
    float a_mem, float a_s0, float a_s1)
{
    // 2 buffers x (TT*2*BN) floats = 2 x 8 KB = 16 KB per block
    __shared__ float buf[2][TT * 2 * BN];

    const int tid = threadIdx.x;          // 0..63 (= lane)
    const int bid = blockIdx.x;           // 0..1023
    const int b   = bid >> 5;             // batch           (2048/64 = 32 slices)
    const int n0  = (bid & 31) << 6;      // neuron slice base

    const float* gin = in + (size_t)b * T_STEPS * STRIDE + n0;
    float* pout      = out + (size_t)b * T_STEPS * N_NEUR + n0 + tid;

    // DMA j (j=0..7) covers (t,s) pairs p = 4j + (lane>>4); 16 lanes x 16 B
    // cover one pair's 256 B of neurons. Global float offset for this lane:
    const int p_lo  = tid >> 4;                       // 0..3 within the DMA
    const int lane4 = (tid & 15) * 4;                 // float offset in group
    // per-pair global offset: t = p>>1 -> (p>>1)*STRIDE, s = p&1 -> (p&1)*N_NEUR
    // computed per j below; lane-invariant part folded there.
    // LDS float offset: pair p at p*64, lane chunk at +lane4 == tid*4.
    const int ldsf = tid * 4;

    // Prologue: stage tile 0 into buf[0]
    #pragma unroll
    for (int j = 0; j < 8; ++j) {
        const int p = 4 * j + p_lo;
        const float* g = gin + (size_t)(p >> 1) * STRIDE + (p & 1) * N_NEUR + lane4;
        async_cp16(g, &buf[0][j * 256 + ldsf]);
    }
    __syncthreads();   // vmcnt(0) drain: tile 0 resident

    float vmem = 0.0f, i0 = 0.0f, i1 = 0.0f;

    #pragma unroll
    for (int k = 0; k < NTILE; ++k) {
        // Issue next tile's DMA into the other buffer (overlaps this tile's compute)
        if (k + 1 < NTILE) {
            const float* gt = gin + (size_t)(k + 1) * TT * STRIDE;
            float* lb = &buf[(k + 1) & 1][0];
            #pragma unroll
            for (int j = 0; j < 8; ++j) {
                const int p = 4 * j + p_lo;
                const float* g = gt + (size_t)(p >> 1) * STRIDE + (p & 1) * N_NEUR + lane4;
                async_cp16(g, lb + j * 256 + ldsf);
            }
        }

        const float* lb = &buf[k & 1][0];
        float* po = pout + (size_t)k * TT * N_NEUR;

        #pragma unroll
        for (int t = 0; t < TT; ++t) {
            // [t][s][n] layout: stride-1 across 64 lanes -> 2-way bank
            // aliasing only (free per m136)
            const float x0 = lb[t * 128 + tid];
            const float x1 = lb[t * 128 + BN + tid];

            // isyn = alpha_syn * isyn + x   (separate mul/add rounding)
            i0 = __fadd_rn(__fmul_rn(a_s0, i0), x0);
            i1 = __fadd_rn(__fmul_rn(a_s1, i1), x1);

            // vmem = alpha_mem * vmem + (i0 + i1)
            const float ssum = __fadd_rn(i0, i1);
            vmem = __fadd_rn(__fmul_rn(a_mem, vmem), ssum);

            // spike = (vmem - 1 > 0); vmem -= spike
            const float vs = __fsub_rn(vmem, 1.0f);
            const bool fired = (vs > 0.0f);
            po[(size_t)t * N_NEUR] = fired ? 1.0f : 0.0f;
            vmem = fired ? vs : vmem;
        }
        __syncthreads();   // drains vmcnt: next tile's DMA complete; buffer reuse safe
    }
}

extern "C" void kernel_launch(void* const* d_in, const int* in_sizes, int n_in,
                              void* d_out, int out_size, void* d_ws, size_t ws_size,
                              hipStream_t stream) {
    const float* in = (const float*)d_in[0];
    float* out = (float*)d_out;

    // Correctly-rounded float32 decay constants of exp on the float32-rounded
    // argument: matches jnp.exp(jnp.float32(-1/tau)).
    const float a_s0  = (float)exp((double)(-1.0f / 5.0f));   // tau_syn[0] = 5
    const float a_s1  = (float)exp((double)(-1.0f / 10.0f));  // tau_syn[1] = 10
    const float a_mem = (float)exp((double)(-1.0f / 10.0f));  // tau_mem    = 10

    dim3 block(64);
    dim3 grid(N_BATCH * (N_NEUR / BN));  // 1024 blocks -> 4 per CU

    snn_scan_kernel<<<grid, block, 0, stream>>>(in, out, a_mem, a_s0, a_s1);
}

// Round 5
// 216.761 us; speedup vs baseline: 1.0042x; 1.0042x over previous
//
#include <hip/hip_runtime.h>
#include <math.h>

// Problem constants (from reference)
#define T_STEPS 256
#define N_NEUR  2048
#define N_BATCH 32
#define STRIDE  (2 * N_NEUR)   // input floats per (b, t)

#define TT      16             // timesteps per LDS tile
#define NTILE   (T_STEPS / TT) // 16 tiles
#define BN      64             // neurons per block (1 wave)
#define NBUF    3              // LDS ring depth (DMA issued 2 tiles ahead)

// Async 16B global->LDS DMA (global_load_lds_dwordx4). LDS dest must be
// wave-uniform base + lane*16 — ldsf = tid*4 floats satisfies this.
__device__ __forceinline__ void async_cp16(const float* g, float* l) {
    __builtin_amdgcn_global_load_lds(
        (const __attribute__((address_space(1))) void*)g,
        (__attribute__((address_space(3))) void*)l, 16, 0, 0);
}

// Explicit staggered wait; memory clobber = compiler ordering fence.
// m135: vmcnt(N) waits until <= N vmem ops outstanding, in-order accounting.
#define WAIT_VMCNT(n) asm volatile("s_waitcnt vmcnt(" #n ")" ::: "memory")

// R5: barrier-free pipeline. R1/R3/R4 all plateaued at ~52-60 us because
// every structure ended each tile in a vmcnt(0)-equivalent drain (barrier or
// compiler batch-wait) — wait-all-then-compute caps throughput at
// queue_latency+compute per tile. Here: single-wave blocks (no barrier
// exists), DMA for tile k+2 issued at tile k, stores deferred to tile end
// (youngest in queue, never waited), and hand-placed s_waitcnt vmcnt(40/32/16)
// so the wave waits only for the 2-tiles-old DMA batch — issue stays
// continuous, stores are never drained.
//
// vmcnt bookkeeping (in-order queue): at tile k's wait, ops younger than
// DMA(k) = stores(k-2):16 + DMA(k+1):8 + stores(k-1):16 + DMA(k+2):8 = 48
// -> wait(40) safe. k=0: younger = D1+D2 = 16. k=1: D2+s0+D3 = 32.
// k=15 (no D17/D16): s13+s14 = 32.
//
// fp discipline: __fmul_rn/__fadd_rn keep mul/add separately rounded
// (reference does not contract to FMA); binary outputs flip on ulp drift.
// Verified absmax=0.0 in R1-R4 — do not touch the arithmetic.
__global__ __launch_bounds__(64) void snn_scan_kernel(
    const float* __restrict__ in,
    float* __restrict__ out,
    float a_mem, float a_s0, float a_s1)
{
    // 3 x 8 KB ring = 24 KB/block; 4 blocks/CU = 96 KB < 160 KB.
    __shared__ float buf[NBUF][TT * 2 * BN];

    const int tid = threadIdx.x;          // 0..63 (= lane)
    const int bid = blockIdx.x;           // 0..1023 -> 4 blocks/CU
    const int b   = bid >> 5;             // batch
    const int n0  = (bid & 31) << 6;      // neuron slice base

    const float* gin = in + (size_t)b * T_STEPS * STRIDE + n0;
    float* pout      = out + (size_t)b * T_STEPS * N_NEUR + n0 + tid;

    // DMA j (j=0..7) covers (t,s) pairs p = 4j + (lane>>4); 16 lanes x 16 B
    // per pair cover its 256 B of neurons.
    const int p_lo  = tid >> 4;
    const int lane4 = (tid & 15) * 4;
    const int ldsf  = tid * 4;            // lane*16 B in LDS

    auto issue = [&](int k) {             // stage tile k into buf[k % NBUF]
        const float* gt = gin + (size_t)k * TT * STRIDE;
        float* lb = &buf[k % NBUF][0];
        #pragma unroll
        for (int j = 0; j < 8; ++j) {
            const int p = 4 * j + p_lo;
            async_cp16(gt + (size_t)(p >> 1) * STRIDE + (p & 1) * N_NEUR + lane4,
                       lb + j * 256 + ldsf);
        }
    };

    issue(0);
    issue(1);

    float vmem = 0.0f, i0 = 0.0f, i1 = 0.0f;

    #pragma unroll
    for (int k = 0; k < NTILE; ++k) {
        if (k + 2 < NTILE) issue(k + 2);

        if      (k == 0)         WAIT_VMCNT(16);
        else if (k == 1)         WAIT_VMCNT(32);
        else if (k == NTILE - 1) WAIT_VMCNT(32);
        else                     WAIT_VMCNT(40);

        const float* lb = &buf[k % NBUF][0];
        float sp[TT];

        #pragma unroll
        for (int t = 0; t < TT; ++t) {
            // [t][s][n] LDS layout, stride-1 across 64 lanes (2-way bank
            // aliasing only — free per m136)
            const float x0 = lb[t * 128 + tid];
            const float x1 = lb[t * 128 + BN + tid];

            // isyn = alpha_syn * isyn + x   (separate mul/add rounding)
            i0 = __fadd_rn(__fmul_rn(a_s0, i0), x0);
            i1 = __fadd_rn(__fmul_rn(a_s1, i1), x1);

            // vmem = alpha_mem * vmem + (i0 + i1)
            const float ssum = __fadd_rn(i0, i1);
            vmem = __fadd_rn(__fmul_rn(a_mem, vmem), ssum);

            // spike = (vmem - 1 > 0); vmem -= spike
            const float vs = __fsub_rn(vmem, 1.0f);
            const bool fired = (vs > 0.0f);
            sp[t] = fired ? 1.0f : 0.0f;
            vmem = fired ? vs : vmem;
        }

        // Deferred burst store: 16 coalesced dword stores, issued after the
        // next tiles' DMAs -> they are the youngest vmcnt ops and are never
        // the target of a wait.
        float* po = pout + (size_t)k * TT * N_NEUR;
        #pragma unroll
        for (int t = 0; t < TT; ++t) {
            po[(size_t)t * N_NEUR] = sp[t];
        }
    }
}

extern "C" void kernel_launch(void* const* d_in, const int* in_sizes, int n_in,
                              void* d_out, int out_size, void* d_ws, size_t ws_size,
                              hipStream_t stream) {
    const float* in = (const float*)d_in[0];
    float* out = (float*)d_out;

    // Correctly-rounded float32 decay constants of exp on the float32-rounded
    // argument: matches jnp.exp(jnp.float32(-1/tau)).
    const float a_s0  = (float)exp((double)(-1.0f / 5.0f));   // tau_syn[0] = 5
    const float a_s1  = (float)exp((double)(-1.0f / 10.0f));  // tau_syn[1] = 10
    const float a_mem = (float)exp((double)(-1.0f / 10.0f));  // tau_mem    = 10

    dim3 block(64);
    dim3 grid(N_BATCH * (N_NEUR / BN));  // 1024 blocks -> 4 per CU

    snn_scan_kernel<<<grid, block, 0, stream>>>(in, out, a_mem, a_s0, a_s1);
}

// Round 6
// 216.759 us; speedup vs baseline: 1.0042x; 1.0000x over previous
//
#include <hip/hip_runtime.h>
#include <math.h>

// Problem constants (from reference)
#define T_STEPS 256
#define N_NEUR  2048
#define N_BATCH 32
#define STRIDE  (2 * N_NEUR)    // input floats per (b, t)

#define BN      64              // neurons per block (1 wave per block)
#define D       32              // register pipeline depth (timesteps)
#define NBLK    (T_STEPS / D)   // 8 blocks of D steps

// R6: deep register-rotation pipeline, no LDS, no barriers, no asm waits.
// Evidence so far: every LDS-DMA variant (R3/R4/R5) is stuck at 52-59 us
// because the compiler inserts vmcnt(0) before ds_reads that depend on
// global_load_lds — a structural per-tile drain. Register loads are the
// one path where LLVM's waitcnt pass is exact (waits only for the register
// consumed). Rotating xa/xb[D] keeps ~2*D = 64 dword loads (16 KB/wave,
// 64 KB/CU at 4 waves/CU) continuously in flight. R2 tried this shape but
// was poisoned by nontemporal loads (L2 bypass -> longer latency; L3 serves
// half the input for free) and a per-j conditional prefetch; both removed.
//
// Occupancy is structurally 1 wave/SIMD (65536 threads = 1024 waves), so
// __launch_bounds__(64,1) makes the ~2*D data VGPRs free.
//
// fp discipline: __fmul_rn/__fadd_rn keep mul/add separately rounded
// (reference does not contract to FMA); binary outputs flip on ulp drift.
// Verified absmax=0.0 in R1-R5 — do not touch the arithmetic.
__global__ __launch_bounds__(64, 1) void snn_scan_kernel(
    const float* __restrict__ in,
    float* __restrict__ out,
    float a_mem, float a_s0, float a_s1)
{
    const int tid = threadIdx.x;          // 0..63
    const int bid = blockIdx.x;           // 0..1023 -> 4 blocks/CU
    const int b   = bid >> 5;             // batch
    const int n0  = (bid & 31) << 6;      // neuron slice base

    const float* pin = in + (size_t)b * T_STEPS * STRIDE + n0 + tid;
    float* pout      = out + (size_t)b * T_STEPS * N_NEUR + n0 + tid;

    float xa[D], xb[D];

    // Prologue: fill the pipeline with the first D timesteps (2*D loads).
    #pragma unroll
    for (int j = 0; j < D; ++j) {
        xa[j] = pin[j * STRIDE];
        xb[j] = pin[j * STRIDE + N_NEUR];
    }

    float vmem = 0.0f, i0 = 0.0f, i1 = 0.0f;

    #pragma unroll 1
    for (int blk = 0; blk < NBLK - 1; ++blk) {
        const int tcur = blk * D;
        const int tnxt = tcur + D;
        #pragma unroll
        for (int j = 0; j < D; ++j) {
            const float x0 = xa[j];
            const float x1 = xb[j];

            // Unconditional rotate-in-place prefetch of step tnxt+j: the
            // loads have no deps on the recurrence, so they issue early and
            // stay in flight ~D steps before consumption.
            xa[j] = pin[(tnxt + j) * STRIDE];
            xb[j] = pin[(tnxt + j) * STRIDE + N_NEUR];

            // isyn = alpha_syn * isyn + x   (separate mul/add rounding)
            i0 = __fadd_rn(__fmul_rn(a_s0, i0), x0);
            i1 = __fadd_rn(__fmul_rn(a_s1, i1), x1);

            // vmem = alpha_mem * vmem + (i0 + i1)
            const float ssum = __fadd_rn(i0, i1);
            vmem = __fadd_rn(__fmul_rn(a_mem, vmem), ssum);

            // spike = (vmem - 1 > 0); vmem -= spike
            const float vs = __fsub_rn(vmem, 1.0f);
            const bool fired = (vs > 0.0f);
            pout[(tcur + j) * N_NEUR] = fired ? 1.0f : 0.0f;
            vmem = fired ? vs : vmem;
        }
    }

    // Epilogue block: consume the last D staged steps, no prefetch.
    {
        const int tcur = (NBLK - 1) * D;
        #pragma unroll
        for (int j = 0; j < D; ++j) {
            const float x0 = xa[j];
            const float x1 = xb[j];

            i0 = __fadd_rn(__fmul_rn(a_s0, i0), x0);
            i1 = __fadd_rn(__fmul_rn(a_s1, i1), x1);

            const float ssum = __fadd_rn(i0, i1);
            vmem = __fadd_rn(__fmul_rn(a_mem, vmem), ssum);

            const float vs = __fsub_rn(vmem, 1.0f);
            const bool fired = (vs > 0.0f);
            pout[(tcur + j) * N_NEUR] = fired ? 1.0f : 0.0f;
            vmem = fired ? vs : vmem;
        }
    }
}

extern "C" void kernel_launch(void* const* d_in, const int* in_sizes, int n_in,
                              void* d_out, int out_size, void* d_ws, size_t ws_size,
                              hipStream_t stream) {
    const float* in = (const float*)d_in[0];
    float* out = (float*)d_out;

    // Correctly-rounded float32 decay constants of exp on the float32-rounded
    // argument: matches jnp.exp(jnp.float32(-1/tau)).
    const float a_s0  = (float)exp((double)(-1.0f / 5.0f));   // tau_syn[0] = 5
    const float a_s1  = (float)exp((double)(-1.0f / 10.0f));  // tau_syn[1] = 10
    const float a_mem = (float)exp((double)(-1.0f / 10.0f));  // tau_mem    = 10

    dim3 block(64);
    dim3 grid(N_BATCH * (N_NEUR / BN));  // 1024 blocks -> 4 per CU

    snn_scan_kernel<<<grid, block, 0, stream>>>(in, out, a_mem, a_s0, a_s1);
}